// Round 3
// baseline (243.612 us; speedup 1.0000x reference)
//
#include <hip/hip_runtime.h>

// RoDAlignMax: features [4,256,64,64] f32, rois [2048,5] f32 -> out [2048,256,9,9] f32
// Grid coords are exactly (7i,7j) (63/9==7 in fp32) => bilinear degenerates to a
// gather; in-ROI samples are zeroed before the 2x2/s1 maxpool.
//
// K1: gather G[b*256+c][i*12+j] = F[b,c,7i,7j]  (rows padded 10->12 so every row
//     base is 16B-aligned; 480 KB -> L2-resident).
// K2: block = roi (256 thr), thread = channel. Stream 10 rows through registers
//     (3 x dwordx4 loads/row), masked vertical max + horizontal max, store 81
//     contiguous dwords per thread (2 x float4 + 1 dword per output row).
//     Wave covers a dense 20 KB output span -> L2 merges into full HBM lines.

#define NR 2048

typedef float f4a4  __attribute__((ext_vector_type(4), aligned(4)));
typedef float f4a16 __attribute__((ext_vector_type(4), aligned(16)));

__global__ __launch_bounds__(128) void rod_gather3(const float* __restrict__ F,
                                                   float* __restrict__ G) {
    int bc = blockIdx.x;                 // b*256 + c, 0..1023
    int t  = threadIdx.x;                // active t < 120
    if (t < 120) {
        int i = (t * 43) >> 9;           // t/12 (valid t<128)
        int j = t - 12 * i;              // t%12
        float v = 0.0f;
        if (j < 10) v = F[(bc << 12) + i * 448 + j * 7];  // F[b,c,7i,7j]
        G[bc * 120 + t] = v;
    }
}

__global__ __launch_bounds__(256) void rod_main3(const float* __restrict__ G,
                                                 const float* __restrict__ rois,
                                                 float* __restrict__ out) {
    const int c = threadIdx.x;
    const int r = blockIdx.x;

    const float x1 = rois[r * 5 + 1] * 0.25f;
    const float y1 = rois[r * 5 + 2] * 0.25f;
    const float x2 = rois[r * 5 + 3] * 0.25f;
    const float y2 = rois[r * 5 + 4] * 0.25f;
    const int   b  = (int)rois[r * 5 + 0];

    // Block-uniform 10-bit in-ROI masks (grid coord s = 7t is exact).
    unsigned inh = 0u, inw = 0u;
    #pragma unroll
    for (int t = 0; t < 10; ++t) {
        float s = 7.0f * (float)t;
        if ((s >= y1) && (s <= y2)) inh |= (1u << t);
        if ((s >= x1) && (s <= x2)) inw |= (1u << t);
    }

    const float* g   = G + (b * 256 + c) * 120;          // 16B-aligned (480B/ch)
    float*       dst = out + (size_t)r * 20736 + c * 81; // 81 contiguous dwords

    float m0[10];
    {
        f4a16 a = *(const f4a16*)(g);
        f4a16 bq = *(const f4a16*)(g + 4);
        float v8 = g[8], v9 = g[9];
        unsigned wm = (inh & 1u) ? inw : 0u;
        float v[10] = {a.x, a.y, a.z, a.w, bq.x, bq.y, bq.z, bq.w, v8, v9};
        #pragma unroll
        for (int j = 0; j < 10; ++j)
            m0[j] = ((wm >> j) & 1u) ? 0.0f : v[j];
    }

    #pragma unroll
    for (int i = 1; i < 10; ++i) {
        const float* gr = g + i * 12;                    // 48B stride: 16B-aligned
        f4a16 a  = *(const f4a16*)(gr);
        f4a16 bq = *(const f4a16*)(gr + 4);
        float v8 = gr[8], v9 = gr[9];
        float v[10] = {a.x, a.y, a.z, a.w, bq.x, bq.y, bq.z, bq.w, v8, v9};

        unsigned wm = ((inh >> i) & 1u) ? inw : 0u;
        float m1[10], t_[10];
        #pragma unroll
        for (int j = 0; j < 10; ++j) {
            m1[j] = ((wm >> j) & 1u) ? 0.0f : v[j];
            t_[j] = fmaxf(m0[j], m1[j]);
        }
        float o[9];
        #pragma unroll
        for (int j = 0; j < 9; ++j) o[j] = fmaxf(t_[j], t_[j + 1]);

        float* dr = dst + (i - 1) * 9;
        *(f4a4*)(dr)     = (f4a4){o[0], o[1], o[2], o[3]};
        *(f4a4*)(dr + 4) = (f4a4){o[4], o[5], o[6], o[7]};
        dr[8] = o[8];

        #pragma unroll
        for (int j = 0; j < 10; ++j) m0[j] = m1[j];
    }
}

extern "C" void kernel_launch(void* const* d_in, const int* in_sizes, int n_in,
                              void* d_out, int out_size, void* d_ws, size_t ws_size,
                              hipStream_t stream) {
    const float* F    = (const float*)d_in[0];   // 4*256*64*64
    const float* rois = (const float*)d_in[1];   // 2048*5
    float*       out  = (float*)d_out;           // 2048*256*81
    float*       G    = (float*)d_ws;            // 1024*120 floats = 491520 B

    rod_gather3<<<dim3(1024), dim3(128), 0, stream>>>(F, G);
    rod_main3<<<dim3(NR), dim3(256), 0, stream>>>(G, rois, out);
}

// Round 4
// 187.577 us; speedup vs baseline: 1.2987x; 1.2987x over previous
//
#include <hip/hip_runtime.h>

// RoDAlignMax: features [4,256,64,64] f32, rois [2048,5] f32 -> out [2048,256,9,9] f32
// Grid coords are exactly (7i,7j) (63/9==7 in fp32) => bilinear degenerates to a
// gather; in-ROI samples are zeroed before the 2x2/s1 maxpool. The ROI mask on a
// 2x2 window is always Hset x Wset (a sub-rectangle), so the masked maxpool is
// computable from precomputed window row-maxes (r0,r1) and col-maxes (c0,c1):
//   no cell inside  -> max(r0, r1)
//   else            -> max(rowCand, colCand, 0)
//     rowCand = (only row0 in) ? r1 : (only row1 in) ? r0 : 0
//     colCand = (only col0 in) ? c1 : (only col1 in) ? c0 : 0
// (masked cells contribute 0 to the pool, hence the max with 0)
//
// K1: T[b*256+c][q] = float4(r0,r1,c0,c1) for window q=i*9+j   (1.33 MB, L2-resident)
// K2: block = roi, 256 thr, flat-element mapping el = tid + 256k:
//     1 dwordx4 table load + ~20 VALU + 1 coalesced nontemporal dword store per output.

#define NR 2048

typedef float f4 __attribute__((ext_vector_type(4)));

__global__ __launch_bounds__(256) void rod_table(const float* __restrict__ F,
                                                 f4* __restrict__ T) {
    int idx = blockIdx.x * 256 + threadIdx.x;          // < 1024*81 = 82944
    if (idx < 82944) {
        unsigned bc = ((unsigned)idx * 25891u) >> 21;  // idx/81 (valid < 110376)
        int q = idx - 81 * (int)bc;
        int i = (q * 57) >> 9;                         // q/9 (valid q<=80)
        int j = q - 9 * i;
        const float* fp = F + ((int)bc << 12) + i * 448 + j * 7;  // F[b,c,7i,7j]
        float v00 = fp[0], v01 = fp[7], v10 = fp[448], v11 = fp[455];
        f4 t;
        t.x = fmaxf(v00, v01);   // r0
        t.y = fmaxf(v10, v11);   // r1
        t.z = fmaxf(v00, v10);   // c0
        t.w = fmaxf(v01, v11);   // c1
        T[idx] = t;
    }
}

__global__ __launch_bounds__(256) void rod_main4(const f4* __restrict__ T,
                                                 const float* __restrict__ rois,
                                                 float* __restrict__ out) {
    const int tid = threadIdx.x;
    const int r   = blockIdx.x;

    const float x1 = rois[r * 5 + 1] * 0.25f;
    const float y1 = rois[r * 5 + 2] * 0.25f;
    const float x2 = rois[r * 5 + 3] * 0.25f;
    const float y2 = rois[r * 5 + 4] * 0.25f;
    const int   b  = (int)rois[r * 5 + 0];

    // Block-uniform 10-bit in-ROI masks (grid coord s = 7t is exact fp32).
    unsigned inh = 0u, inw = 0u;
    #pragma unroll
    for (int t = 0; t < 10; ++t) {
        float s = 7.0f * (float)t;
        if ((s >= y1) && (s <= y2)) inh |= (1u << t);
        if ((s >= x1) && (s <= x2)) inw |= (1u << t);
    }

    const f4* Tb  = T + b * 20736;                 // b*256*81 windows
    float*    dst = out + (size_t)r * 20736;

    unsigned c0 = ((unsigned)tid * 25891u) >> 21;  // tid/81
    int q  = tid - 81 * (int)c0;                   // window index within channel
    int el = tid;

    #pragma unroll 3
    for (int k = 0; k < 81; ++k) {
        f4 t = Tb[el];                             // (r0,r1,c0,c1), dwordx4, L2-hot
        int i = (q * 57) >> 9;
        int j = q - 9 * i;
        unsigned hb = (inh >> i) & 3u;             // rows i,i+1 inside-H flags
        unsigned wb = (inw >> j) & 3u;             // cols j,j+1 inside-W flags

        float rowA = (hb == 1u) ? t.y : ((hb == 2u) ? t.x : 0.0f);
        float colA = (wb == 1u) ? t.w : ((wb == 2u) ? t.z : 0.0f);
        float inMax  = fmaxf(fmaxf(rowA, colA), 0.0f);
        float outMax = fmaxf(t.x, t.y);
        bool  anyIn  = (hb != 0u) && (wb != 0u);

        __builtin_nontemporal_store(anyIn ? inMax : outMax, dst + el);

        el += 256;
        q += 13; q = (q >= 81) ? q - 81 : q;       // q = el % 81, incrementally
    }
}

extern "C" void kernel_launch(void* const* d_in, const int* in_sizes, int n_in,
                              void* d_out, int out_size, void* d_ws, size_t ws_size,
                              hipStream_t stream) {
    const float* F    = (const float*)d_in[0];   // 4*256*64*64
    const float* rois = (const float*)d_in[1];   // 2048*5
    float*       out  = (float*)d_out;           // 2048*256*81
    f4*          T    = (f4*)d_ws;               // 82944 * 16 B = 1.33 MB

    rod_table<<<dim3(324), dim3(256), 0, stream>>>(F, T);
    rod_main4<<<dim3(NR), dim3(256), 0, stream>>>(T, rois, out);
}